// Round 1
// baseline (173.036 us; speedup 1.0000x reference)
//
#include <hip/hip_runtime.h>
#include <hip/hip_bf16.h>

#define BATCH 16
#define CI 64
#define CO 64
#define H 128
#define W 128
#define HO 126
#define WO 126
#define HW (H * W)

typedef short bfrag __attribute__((ext_vector_type(8)));   // 8 bf16 = 4 VGPRs
typedef float ffrag __attribute__((ext_vector_type(4)));   // 4 fp32 acc

static __device__ __forceinline__ unsigned short f2bf(float f) {
    unsigned u = __float_as_uint(f);
    u += 0x7fffu + ((u >> 16) & 1u);      // RNE
    return (unsigned short)(u >> 16);
}

// prepass: w[b][co][ci][dy][dx] fp32 -> w_t[b][s][co][ci] bf16  (s = dy*3+dx)
__global__ void wt_prepass(const float* __restrict__ w, unsigned short* __restrict__ w_t) {
    int i = blockIdx.x * 256 + threadIdx.x;          // 589824 total
    int ci = i & 63;
    int co = (i >> 6) & 63;
    int bs = i >> 12;
    int b = bs / 9, s = bs - b * 9;
    w_t[i] = f2bf(w[(((b * 64 + co) * 64 + ci) * 9) + s]);
}

// Persistent ring-pipelined dynconv:
//  - 1 block/CU (96 KB LDS), 512 threads = 8 waves (co-half x out-row x col-half)
//  - block (gx,b) owns 4 row-pair units; LDS = ring of 6 row-slabs, slab = y%6
//  - per unit: issue float4 x-loads for unit i+1  ->  9 shift-GEMMs on slabs
//    y0..y0+3  ->  cvt+ds_write slabs (y0+4,y0+5)%6  ->  barrier  ->  stores
//    (drain under next unit's compute).  One barrier/unit: write slabs are
//    disjoint from this unit's read slabs; prior-unit reads ordered by the
//    previous barrier.
//  - chunk swizzle col*8 + (o ^ (col&7)) unchanged: B-frag ds_read_b128 stays
//    conflict-free; 4-col/thread staging writes are 4-way (32 instr/unit, ok).
__launch_bounds__(512, 2)
__global__ void dynconv_fused(const float* __restrict__ x,
                              const unsigned short* __restrict__ w_t,
                              const float* __restrict__ bias,
                              float* __restrict__ out) {
    __shared__ __align__(16) unsigned short xs[6 * 8192];   // 6 row-slabs x 16 KB

    const int tid = threadIdx.x;
    const int gx  = blockIdx.x;              // 16 row-ranges
    const int b   = blockIdx.y;
    const int nunits = (gx == 15) ? 3 : 4;   // 63 row-pairs total

    const int wave = tid >> 6, lane = tid & 63;
    const int l16 = lane & 15, lq = lane >> 4;
    const int wm = wave & 1;                 // co half
    const int wn = (wave >> 1) & 1;          // output row within unit
    const int wc = wave >> 2;                // col half (64 cols)

    // fixed staging role: 2 rows x 8 octets x 32 col-quads = 512 threads
    const int st_r  = tid >> 8;
    const int st_o  = (tid >> 5) & 7;
    const int st_cg = tid & 31;

    const float* xb   = x + (size_t)b * CI * HW;
    const float* stp0 = xb + (size_t)(st_o * 8) * HW + st_cg * 4;

    // ---- prologue: stage rows y00..y00+3 (loads+writes fused, once per block)
    const int y00 = gx * 8;
    #pragma unroll
    for (int pp = 0; pp < 2; ++pp) {
        const int y = y00 + pp * 2 + st_r;
        const float* p = stp0 + (size_t)y * W;
        float4 v[8];
        #pragma unroll
        for (int e = 0; e < 8; ++e) v[e] = *(const float4*)(p + (size_t)e * HW);
        const int slab = (y % 6) * 8192;
        #pragma unroll
        for (int k = 0; k < 4; ++k) {
            const int col = st_cg * 4 + k;
            unsigned int u[4];
            #pragma unroll
            for (int e = 0; e < 4; ++e) {
                __hip_bfloat162 h2 = __float22bfloat162_rn(
                    make_float2(((const float*)&v[2 * e])[k], ((const float*)&v[2 * e + 1])[k]));
                u[e] = *(unsigned int*)&h2;
            }
            *(uint4*)&xs[slab + (col * 8 + (st_o ^ (col & 7))) * 8] = *(const uint4*)u;
        }
    }

    // ---- block-invariant: bias regs + shift-0 A-frags (w_t L2-resident)
    const bfrag* wtb = (const bfrag*)w_t + (size_t)(b * 9) * 512;
    const int co_b = wm * 32 + l16;
    float bv[2][4];
    #pragma unroll
    for (int mt = 0; mt < 2; ++mt)
        #pragma unroll
        for (int r = 0; r < 4; ++r)
            bv[mt][r] = bias[b * 64 + wm * 32 + mt * 16 + lq * 4 + r];

    bfrag acur[4], anxt[4];
    #pragma unroll
    for (int ks = 0; ks < 2; ++ks)
        #pragma unroll
        for (int mt = 0; mt < 2; ++mt)
            acur[ks * 2 + mt] = wtb[(co_b + mt * 16) * 8 + ks * 4 + lq];

    __syncthreads();

    for (int j = 0; j < nunits; ++j) {
        const int y0 = (gx * 4 + j) * 2;
        const bool hn = (j + 1) < nunits;
        const int yN = y0 + 4 + st_r;

        // 1. issue next-unit staging loads — in flight across the whole compute
        float4 v[8];
        if (hn) {
            const float* p = stp0 + (size_t)yN * W;
            #pragma unroll
            for (int e = 0; e < 8; ++e) v[e] = *(const float4*)(p + (size_t)e * HW);
        }

        // 2. compute: 9 shift-GEMMs from slabs (y0..y0+3)%6
        ffrag acc[2][4];
        #pragma unroll
        for (int mt = 0; mt < 2; ++mt)
            #pragma unroll
            for (int nt = 0; nt < 4; ++nt)
                acc[mt][nt] = (ffrag){0.f, 0.f, 0.f, 0.f};

        for (int s = 0; s < 9; ++s) {
            const int sn = (s == 8) ? 0 : s + 1;       // wraps to shift 0 for next unit
            const bfrag* wnx = wtb + sn * 512;
            #pragma unroll
            for (int ks = 0; ks < 2; ++ks)
                #pragma unroll
                for (int mt = 0; mt < 2; ++mt)
                    anxt[ks * 2 + mt] = wnx[(co_b + mt * 16) * 8 + ks * 4 + lq];

            const int dy = s / 3, dx = s - dy * 3;
            const int slab = ((y0 + wn + dy) % 6) * 8192;
            #pragma unroll
            for (int ks = 0; ks < 2; ++ks) {
                const int o = ks * 4 + lq;
                #pragma unroll
                for (int nt = 0; nt < 4; ++nt) {
                    int colx = wc * 64 + nt * 16 + l16 + dx;
                    if (colx > 127) colx = 127;        // clamped lanes -> discarded cols
                    const bfrag bf = *(const bfrag*)&xs[slab + (colx * 8 + (o ^ (colx & 7))) * 8];
                    acc[0][nt] = __builtin_amdgcn_mfma_f32_16x16x32_bf16(acur[ks * 2 + 0], bf, acc[0][nt], 0, 0, 0);
                    acc[1][nt] = __builtin_amdgcn_mfma_f32_16x16x32_bf16(acur[ks * 2 + 1], bf, acc[1][nt], 0, 0, 0);
                }
            }
            #pragma unroll
            for (int q = 0; q < 4; ++q) acur[q] = anxt[q];
        }

        // 3. write staged rows for next unit (slabs (y0+4,y0+5)%6 — disjoint
        //    from this unit's read slabs; compiler waits the x-loads here)
        if (hn) {
            const int slab = (yN % 6) * 8192;
            #pragma unroll
            for (int k = 0; k < 4; ++k) {
                const int col = st_cg * 4 + k;
                unsigned int u[4];
                #pragma unroll
                for (int e = 0; e < 4; ++e) {
                    __hip_bfloat162 h2 = __float22bfloat162_rn(
                        make_float2(((const float*)&v[2 * e])[k], ((const float*)&v[2 * e + 1])[k]));
                    u[e] = *(unsigned int*)&h2;
                }
                *(uint4*)&xs[slab + (col * 8 + (st_o ^ (col & 7))) * 8] = *(const uint4*)u;
            }
        }
        __syncthreads();

        // 4. epilogue AFTER the barrier: stores drain under next unit's compute
        const int oy = y0 + wn;
        #pragma unroll
        for (int mt = 0; mt < 2; ++mt) {
            #pragma unroll
            for (int r = 0; r < 4; ++r) {
                float* op = out + ((size_t)(b * 64 + wm * 32 + mt * 16 + lq * 4 + r) * HO + oy) * WO;
                const float bvv = bv[mt][r];
                #pragma unroll
                for (int nt = 0; nt < 4; ++nt) {
                    const int ox = wc * 64 + nt * 16 + l16;
                    if (ox < WO) op[ox] = acc[mt][nt][r] + bvv;
                }
            }
        }
    }
}

extern "C" void kernel_launch(void* const* d_in, const int* in_sizes, int n_in,
                              void* d_out, int out_size, void* d_ws, size_t ws_size,
                              hipStream_t stream) {
    const float* x    = (const float*)d_in[0];
    const float* w    = (const float*)d_in[1];
    const float* bias = (const float*)d_in[2];
    float* out        = (float*)d_out;

    unsigned short* w_t = (unsigned short*)d_ws;   // 1,179,648 B

    wt_prepass<<<dim3(589824 / 256), dim3(256), 0, stream>>>(w, w_t);
    dynconv_fused<<<dim3(16, BATCH), dim3(512), 0, stream>>>(x, w_t, bias, out);
}

// Round 2
// 138.025 us; speedup vs baseline: 1.2537x; 1.2537x over previous
//
#include <hip/hip_runtime.h>
#include <hip/hip_bf16.h>

#define BATCH 16
#define CI 64
#define CO 64
#define H 128
#define W 128
#define HO 126
#define WO 126
#define HW (H * W)

typedef short bfrag __attribute__((ext_vector_type(8)));   // 8 bf16 = 4 VGPRs
typedef float ffrag __attribute__((ext_vector_type(4)));   // 4 fp32 acc

static __device__ __forceinline__ unsigned short f2bf(float f) {
    unsigned u = __float_as_uint(f);
    u += 0x7fffu + ((u >> 16) & 1u);      // RNE
    return (unsigned short)(u >> 16);
}

// prepass: w[b][co][ci][dy][dx] fp32 -> w_t[b][s][co][ci] bf16  (s = dy*3+dx)
__global__ void wt_prepass(const float* __restrict__ w, unsigned short* __restrict__ w_t) {
    int i = blockIdx.x * 256 + threadIdx.x;          // 589824 total
    int ci = i & 63;
    int co = (i >> 6) & 63;
    int bs = i >> 12;
    int b = bs / 9, s = bs - b * 9;
    w_t[i] = f2bf(w[(((b * 64 + co) * 64 + ci) * 9) + s]);
}

// cvt + swizzled LDS write of one staged row fragment.
// Role mapping (o fast, colq slow) => per wave the 64 lanes write 8 runs of
// 128B contiguous LDS (swz spans full octet) -> conflict-free ds_write_b128.
static __device__ __forceinline__ void stage_write(unsigned short* __restrict__ slabp,
                                                   const float4* __restrict__ v,
                                                   int st_o, int st_cg) {
    #pragma unroll
    for (int k = 0; k < 4; ++k) {
        const int col = st_cg * 4 + k;
        unsigned int u[4];
        #pragma unroll
        for (int e = 0; e < 4; ++e) {
            __hip_bfloat162 h2 = __float22bfloat162_rn(make_float2(
                ((const float*)&v[2 * e])[k], ((const float*)&v[2 * e + 1])[k]));
            u[e] = *(unsigned int*)&h2;          // low = even ci
        }
        *(uint4*)&slabp[(col * 8 + (st_o ^ (col & 7))) * 8] = *(const uint4*)u;
    }
}

// Ring-pipelined dynconv, zero global loads inside the unit loop:
//  - grid (16,16): 1 block/CU, 512 threads = 8 waves = 4 co-quarters x 2 rows
//  - A-frags (9 shifts x 2 ks, this wave's co-quarter) fully register-resident
//    (72 VGPR) -> unit loop is pure ds_read+MFMA; the float4 x-loads issued at
//    unit top are never force-drained by in-order vmcnt until stage_write.
//  - LDS ring of 6 row-slabs (slab = row%6); one raw s_barrier per unit
//    (write slabs (y+4,y+5)%6 disjoint from read slabs y..y+3).
//  - stores after the barrier: full 126-col rows per wave (L2 sector-merge
//    friendly, R0-verified write pattern), drain under next unit's compute.
__launch_bounds__(512, 2)
__global__ void dynconv_fused(const float* __restrict__ x,
                              const unsigned short* __restrict__ w_t,
                              const float* __restrict__ bias,
                              float* __restrict__ out) {
    __shared__ __align__(16) unsigned short xs[6 * 8192];   // 6 row-slabs x 16 KB

    const int tid = threadIdx.x;
    const int gx  = blockIdx.x;              // 16 row-ranges
    const int b   = blockIdx.y;
    const int nunits = (gx == 15) ? 3 : 4;   // 63 row-pairs total
    const int y00 = gx * 8;

    const int wave = tid >> 6, lane = tid & 63;
    const int l16 = lane & 15, lq = lane >> 4;
    const int wm = wave & 3;                 // co quarter (16 co)
    const int wn = wave >> 2;                // output row within unit

    // staging role: o fast, col-quad slow, row = tid>>8
    const int st_o  = tid & 7;
    const int st_cg = (tid >> 3) & 31;
    const int st_r  = tid >> 8;

    const float* stp = x + (size_t)b * CI * HW + (size_t)(st_o * 8) * HW + st_cg * 4;

    // ---- A-frag preload: all 9 shifts x 2 ks for this wave's co-quarter
    const bfrag* wtb = (const bfrag*)w_t + (size_t)(b * 9) * 512;
    const int co_b = wm * 16 + l16;
    bfrag a[9][2];
    #pragma unroll
    for (int s = 0; s < 9; ++s)
        #pragma unroll
        for (int ks = 0; ks < 2; ++ks)
            a[s][ks] = wtb[s * 512 + co_b * 8 + ks * 4 + lq];

    float bv[4];
    #pragma unroll
    for (int r = 0; r < 4; ++r)
        bv[r] = bias[b * 64 + wm * 16 + lq * 4 + r];

    // ---- prologue: stage rows y00..y00+3 into slabs 0..3
    {
        float4 v0[8], v1[8];
        const float* p0 = stp + (size_t)(y00 + st_r) * W;
        const float* p1 = stp + (size_t)(y00 + 2 + st_r) * W;
        #pragma unroll
        for (int e = 0; e < 8; ++e) v0[e] = *(const float4*)(p0 + (size_t)e * HW);
        #pragma unroll
        for (int e = 0; e < 8; ++e) v1[e] = *(const float4*)(p1 + (size_t)e * HW);
        stage_write(&xs[(st_r) * 8192], v0, st_o, st_cg);
        stage_write(&xs[(2 + st_r) * 8192], v1, st_o, st_cg);
    }
    asm volatile("s_waitcnt lgkmcnt(0)" ::: "memory");
    __builtin_amdgcn_s_barrier();
    __builtin_amdgcn_sched_barrier(0);

    for (int j = 0; j < nunits; ++j) {
        const bool hn = (j + 1) < nunits;
        const int u2j = 2 * j;

        // 1. issue next-unit x loads (stay in flight through all of compute —
        //    no other global load will force an in-order vmcnt drain)
        float4 v[8];
        if (hn) {
            const float* p = stp + (size_t)(y00 + u2j + 4 + st_r) * W;
            #pragma unroll
            for (int e = 0; e < 8; ++e) v[e] = *(const float4*)(p + (size_t)e * HW);
        }

        // 2. compute: 9 shift-GEMMs, pure ds_read + MFMA
        ffrag acc[8];
        #pragma unroll
        for (int nt = 0; nt < 8; ++nt) acc[nt] = (ffrag){0.f, 0.f, 0.f, 0.f};

        #pragma unroll
        for (int s = 0; s < 9; ++s) {
            const int dy = s / 3, dx = s - dy * 3;
            int t = u2j + wn + dy;
            if (t >= 6) t -= 6;
            const unsigned short* slabp = &xs[t * 8192];
            #pragma unroll
            for (int ks = 0; ks < 2; ++ks) {
                const int o = ks * 4 + lq;
                #pragma unroll
                for (int nt = 0; nt < 8; ++nt) {
                    int colx = nt * 16 + l16 + dx;
                    if (colx > 127) colx = 127;    // clamped lanes -> discarded cols
                    const bfrag bf = *(const bfrag*)&slabp[(colx * 8 + (o ^ (colx & 7))) * 8];
                    acc[nt] = __builtin_amdgcn_mfma_f32_16x16x32_bf16(a[s][ks], bf, acc[nt], 0, 0, 0);
                }
            }
        }

        // 3. cvt + write staged rows for unit j+1 (slabs (y+4,y+5)%6, disjoint
        //    from this unit's reads); then the single per-unit barrier
        if (hn) {
            int t = u2j + 4 + st_r;
            if (t >= 6) t -= 6;
            stage_write(&xs[t * 8192], v, st_o, st_cg);
            asm volatile("s_waitcnt lgkmcnt(0)" ::: "memory");
            __builtin_amdgcn_s_barrier();
            __builtin_amdgcn_sched_barrier(0);
        }

        // 4. stores after the barrier: full rows, drain under next compute
        const int oy = y00 + u2j + wn;
        #pragma unroll
        for (int r = 0; r < 4; ++r) {
            float* op = out + ((size_t)(b * 64 + wm * 16 + lq * 4 + r) * HO + oy) * WO;
            const float bvv = bv[r];
            #pragma unroll
            for (int nt = 0; nt < 8; ++nt) {
                const int ox = nt * 16 + l16;
                if (ox < WO) op[ox] = acc[nt][r] + bvv;
            }
        }
    }
}

extern "C" void kernel_launch(void* const* d_in, const int* in_sizes, int n_in,
                              void* d_out, int out_size, void* d_ws, size_t ws_size,
                              hipStream_t stream) {
    const float* x    = (const float*)d_in[0];
    const float* w    = (const float*)d_in[1];
    const float* bias = (const float*)d_in[2];
    float* out        = (float*)d_out;

    unsigned short* w_t = (unsigned short*)d_ws;   // 1,179,648 B

    wt_prepass<<<dim3(589824 / 256), dim3(256), 0, stream>>>(w, w_t);
    dynconv_fused<<<dim3(16, BATCH), dim3(512), 0, stream>>>(x, w_t, bias, out);
}

// Round 3
// 134.156 us; speedup vs baseline: 1.2898x; 1.0288x over previous
//
#include <hip/hip_runtime.h>
#include <hip/hip_bf16.h>

#define BATCH 16
#define CI 64
#define CO 64
#define H 128
#define W 128
#define HO 126
#define WO 126
#define HW (H * W)

typedef short bfrag __attribute__((ext_vector_type(8)));   // 8 bf16 = 4 VGPRs
typedef float ffrag __attribute__((ext_vector_type(4)));   // 4 fp32 acc

static __device__ __forceinline__ unsigned short f2bf(float f) {
    unsigned u = __float_as_uint(f);
    u += 0x7fffu + ((u >> 16) & 1u);      // RNE
    return (unsigned short)(u >> 16);
}

// prepass: w[b][co][ci][dy][dx] fp32 -> w_t[b][s][co][ci] bf16  (s = dy*3+dx)
__global__ void wt_prepass(const float* __restrict__ w, unsigned short* __restrict__ w_t) {
    int i = blockIdx.x * 256 + threadIdx.x;          // 589824 total
    int ci = i & 63;
    int co = (i >> 6) & 63;
    int bs = i >> 12;
    int b = bs / 9, s = bs - b * 9;
    w_t[i] = f2bf(w[(((b * 64 + co) * 64 + ci) * 9) + s]);
}

// cvt + swizzled LDS write of one staged row fragment.
// Per wave: lanes = 8 octets x 8 col-quads; for each k the 8-octet group
// writes 128B contiguous (swz spans the octet) -> conflict-free ds_write_b128
// (R2-verified: SQ_LDS_BANK_CONFLICT == 0).
static __device__ __forceinline__ void stage_write(unsigned short* __restrict__ slabp,
                                                   const float4* __restrict__ v,
                                                   int st_o, int st_cg) {
    #pragma unroll
    for (int k = 0; k < 4; ++k) {
        const int col = st_cg * 4 + k;
        unsigned int u[4];
        #pragma unroll
        for (int e = 0; e < 4; ++e) {
            __hip_bfloat162 h2 = __float22bfloat162_rn(make_float2(
                ((const float*)&v[2 * e])[k], ((const float*)&v[2 * e + 1])[k]));
            u[e] = *(unsigned int*)&h2;          // low = even ci
        }
        *(uint4*)&slabp[(col * 8 + (st_o ^ (col & 7))) * 8] = *(const uint4*)u;
    }
}

// Ring-pipelined dynconv, 2 blocks/CU for HBM duty-cycle:
//  - grid (32,16) = 512 blocks = exactly 2/CU (64 KB LDS each, 256 thr = 4
//    waves = 4 co-quarters).  While one block sits in its post-load window
//    (cvt/ds_write/barrier/stores), the co-resident block's loads keep HBM
//    demand outstanding -> aggregate BW ~continuous (R2 was 1 block/CU, 40%
//    duty, 2.5 TB/s).
//  - unit = 1 output row; LDS ring of 4 row-slabs (slab = (j+dy)&3, y0%4==0).
//    Unit j reads slabs j..j+2, prefetch row y0+j+3 -> slab (j+3)&3: disjoint
//    from current reads; overwritten row y0+j-1 last read before unit j-1's
//    barrier -> one raw s_barrier per unit, race-free.
//  - A-frags (9 shifts x 2 ks) register-resident; unit loop has zero global
//    loads except the prefetch itself -> no in-order-vmcnt poisoning.
__launch_bounds__(256, 2)
__global__ void dynconv_fused(const float* __restrict__ x,
                              const unsigned short* __restrict__ w_t,
                              const float* __restrict__ bias,
                              float* __restrict__ out) {
    __shared__ __align__(16) unsigned short xs[4 * 8192];   // 4 row-slabs x 16 KB

    const int tid = threadIdx.x;
    const int gx  = blockIdx.x;              // 0..31 row-ranges
    const int b   = blockIdx.y;
    const int y0  = gx * 4;
    const int nunits = (gx == 31) ? 2 : 4;   // 126 output rows total

    const int wave = tid >> 6, lane = tid & 63;
    const int l16 = lane & 15, lq = lane >> 4;

    // staging role: o fast, col-quad slow
    const int st_o  = tid & 7;
    const int st_cg = tid >> 3;              // 0..31

    const float* stp = x + (size_t)b * CI * HW + (size_t)(st_o * 8) * HW + st_cg * 4;

    // ---- A-frag preload: all 9 shifts x 2 ks for this wave's co-quarter
    const bfrag* wtb = (const bfrag*)w_t + (size_t)(b * 9) * 512;
    const int co_b = wave * 16 + l16;
    bfrag a[9][2];
    #pragma unroll
    for (int s = 0; s < 9; ++s)
        #pragma unroll
        for (int ks = 0; ks < 2; ++ks)
            a[s][ks] = wtb[s * 512 + co_b * 8 + ks * 4 + lq];

    float bv[4];
    #pragma unroll
    for (int r = 0; r < 4; ++r)
        bv[r] = bias[b * 64 + wave * 16 + lq * 4 + r];

    // ---- prologue: stage rows y0..y0+2 into slabs 0..2 (y0 % 4 == 0)
    {
        float4 v[3][8];
        #pragma unroll
        for (int rr = 0; rr < 3; ++rr) {
            const float* p = stp + (size_t)(y0 + rr) * W;
            #pragma unroll
            for (int e = 0; e < 8; ++e) v[rr][e] = *(const float4*)(p + (size_t)e * HW);
        }
        #pragma unroll
        for (int rr = 0; rr < 3; ++rr)
            stage_write(&xs[rr * 8192], v[rr], st_o, st_cg);
    }
    asm volatile("s_waitcnt lgkmcnt(0)" ::: "memory");
    __builtin_amdgcn_s_barrier();
    __builtin_amdgcn_sched_barrier(0);

    for (int j = 0; j < nunits; ++j) {
        const bool hn = (j + 1) < nunits;

        // 1. issue next-row loads; they stay in flight through compute
        float4 v[8];
        if (hn) {
            const float* p = stp + (size_t)(y0 + j + 3) * W;
            #pragma unroll
            for (int e = 0; e < 8; ++e) v[e] = *(const float4*)(p + (size_t)e * HW);
        }
        __builtin_amdgcn_sched_barrier(0);   // pin load-issue before compute

        // 2. compute one output row: 9 shift-GEMMs, pure ds_read + MFMA
        ffrag acc[8];
        #pragma unroll
        for (int nt = 0; nt < 8; ++nt) acc[nt] = (ffrag){0.f, 0.f, 0.f, 0.f};

        #pragma unroll
        for (int s = 0; s < 9; ++s) {
            const int dy = s / 3, dx = s - dy * 3;
            const unsigned short* slabp = &xs[((j + dy) & 3) * 8192];
            #pragma unroll
            for (int ks = 0; ks < 2; ++ks) {
                const int o = ks * 4 + lq;
                #pragma unroll
                for (int nt = 0; nt < 8; ++nt) {
                    int colx = nt * 16 + l16 + dx;
                    if (colx > 127) colx = 127;    // clamped lanes -> discarded cols
                    const bfrag bf = *(const bfrag*)&slabp[(colx * 8 + (o ^ (colx & 7))) * 8];
                    acc[nt] = __builtin_amdgcn_mfma_f32_16x16x32_bf16(a[s][ks], bf, acc[nt], 0, 0, 0);
                }
            }
        }

        // 3. cvt + write prefetched row to slab (j+3)&3, then per-unit barrier
        if (hn) {
            stage_write(&xs[((j + 3) & 3) * 8192], v, st_o, st_cg);
            asm volatile("s_waitcnt lgkmcnt(0)" ::: "memory");
            __builtin_amdgcn_s_barrier();
            __builtin_amdgcn_sched_barrier(0);
        }

        // 4. stores after the barrier: drain under next unit's compute
        const int oy = y0 + j;
        #pragma unroll
        for (int r = 0; r < 4; ++r) {
            float* op = out + ((size_t)(b * 64 + wave * 16 + lq * 4 + r) * HO + oy) * WO;
            const float bvv = bv[r];
            #pragma unroll
            for (int nt = 0; nt < 8; ++nt) {
                const int ox = nt * 16 + l16;
                if (ox < WO) op[ox] = acc[nt][r] + bvv;
            }
        }
    }
}

extern "C" void kernel_launch(void* const* d_in, const int* in_sizes, int n_in,
                              void* d_out, int out_size, void* d_ws, size_t ws_size,
                              hipStream_t stream) {
    const float* x    = (const float*)d_in[0];
    const float* w    = (const float*)d_in[1];
    const float* bias = (const float*)d_in[2];
    float* out        = (float*)d_out;

    unsigned short* w_t = (unsigned short*)d_ws;   // 1,179,648 B

    wt_prepass<<<dim3(589824 / 256), dim3(256), 0, stream>>>(w, w_t);
    dynconv_fused<<<dim3(32, BATCH), dim3(256), 0, stream>>>(x, w_t, bias, out);
}